// Round 8
// baseline (252.747 us; speedup 1.0000x reference)
//
#include <hip/hip_runtime.h>
#include <hip/hip_bf16.h>

#define N_NODES 50000
#define N_EDGES 800000
#define F_IN    128
#define HC      128      // H*C
#define NR      16       // node ranges
#define RSZ     3125     // nodes per range
#define NCH     16       // edge chunks
#define CHSZ    50000    // edges per chunk

typedef __attribute__((ext_vector_type(8))) short bf16x8;
typedef __attribute__((ext_vector_type(4))) float f32x4;

__device__ __forceinline__ float bf2f(unsigned int u16) {
    return __uint_as_float(u16 << 16);
}
__device__ __forceinline__ unsigned int f2bf(float f) {
    unsigned int u = __float_as_uint(f);
    return (u + 0x7fffu + ((u >> 16) & 1u)) >> 16;   // RNE
}

// ---------------------------------------------------------------------------
// K_hist: blocks 0..255 = LDS sub-histogram for (range r=bid&15, chunk
// c=bid>>4): stream chunk's dsts, LDS-atomic count those in range, write
// partials to part[node*16+c]. Blocks 256..271: pack [Wg|Ws] -> Bfrag
// (MFMA-B fragment-major bf16). NO global atomics.
// ---------------------------------------------------------------------------
__global__ __launch_bounds__(256) void k_hist(
    const int* __restrict__ dst,
    const float* __restrict__ Wg, const float* __restrict__ Ws,
    unsigned short* __restrict__ Bfrag, int* __restrict__ part)
{
    const int bid = blockIdx.x;
    const int tid = threadIdx.x;
    if (bid < 256) {
        __shared__ int hist[RSZ];
        const int r = bid & 15, c = bid >> 4;
        const int nb = r * RSZ;
        for (int i = tid; i < RSZ; i += 256) hist[i] = 0;
        __syncthreads();
        const int4* d4 = (const int4*)(dst + c * CHSZ);
        for (int i = tid; i < CHSZ / 4; i += 256) {
            const int4 v = d4[i];
            int b;
            b = v.x - nb; if ((unsigned)b < (unsigned)RSZ) atomicAdd(&hist[b], 1);
            b = v.y - nb; if ((unsigned)b < (unsigned)RSZ) atomicAdd(&hist[b], 1);
            b = v.z - nb; if ((unsigned)b < (unsigned)RSZ) atomicAdd(&hist[b], 1);
            b = v.w - nb; if ((unsigned)b < (unsigned)RSZ) atomicAdd(&hist[b], 1);
        }
        __syncthreads();
        for (int i = tid; i < RSZ; i += 256)
            part[(size_t)(nb + i) * NCH + c] = hist[i];
    } else {
        const int g = (bid - 256) * 256 + tid;
        if (g < 4096) {
            const int lane = g & 63;
            const int kq = (g >> 6) & 3;
            const int nt = g >> 8;           // 0..15
            const int cc = nt * 16 + (lane & 15);
            const int kbase = kq * 32 + (lane >> 4) * 8;
            const float* Wsel = (cc < 128) ? (Wg + cc) : (Ws + cc - 128);
            unsigned int pk[4];
#pragma unroll
            for (int p = 0; p < 4; p++) {
                const float v0 = Wsel[(size_t)(kbase + 2 * p) * HC];
                const float v1 = Wsel[(size_t)(kbase + 2 * p + 1) * HC];
                pk[p] = f2bf(v0) | (f2bf(v1) << 16);
            }
            *(uint4*)(Bfrag + (size_t)g * 8) = make_uint4(pk[0], pk[1], pk[2], pk[3]);
        }
    }
}

// ---------------------------------------------------------------------------
// K_scanA (merge fused): per node, chunk-exclusive-prefix part[] in place,
// counts[n] = total; block-exclusive-scan of (counts+1) -> row_start; block
// sums -> bsum. Multi-block on purpose (single-block scan = R5 regression).
// ---------------------------------------------------------------------------
__global__ __launch_bounds__(256) void k_scanA(
    int* __restrict__ part, int* __restrict__ counts,
    int* __restrict__ row_start, int* __restrict__ bsum)
{
    __shared__ int s[256];
    const int tid = threadIdx.x;
    const int base = blockIdx.x * 1024 + tid * 4;
    int v[4]; int t = 0;
#pragma unroll
    for (int j = 0; j < 4; j++) {
        const int idx = base + j;
        if (idx < N_NODES) {
            int4* p = (int4*)(part + (size_t)idx * NCH);
            int4 a0 = p[0], a1 = p[1], a2 = p[2], a3 = p[3];
            int vv[16] = {a0.x, a0.y, a0.z, a0.w, a1.x, a1.y, a1.z, a1.w,
                          a2.x, a2.y, a2.z, a2.w, a3.x, a3.y, a3.z, a3.w};
            int run = 0;
#pragma unroll
            for (int c = 0; c < 16; c++) { const int q = vv[c]; vv[c] = run; run += q; }
            p[0] = make_int4(vv[0], vv[1], vv[2], vv[3]);
            p[1] = make_int4(vv[4], vv[5], vv[6], vv[7]);
            p[2] = make_int4(vv[8], vv[9], vv[10], vv[11]);
            p[3] = make_int4(vv[12], vv[13], vv[14], vv[15]);
            counts[idx] = run;
            v[j] = run + 1;                  // +1 = self-loop
        } else v[j] = 0;
        t += v[j];
    }
    s[tid] = t;
    __syncthreads();
    for (int off = 1; off < 256; off <<= 1) {
        int add = (tid >= off) ? s[tid - off] : 0;
        __syncthreads();
        s[tid] += add;
        __syncthreads();
    }
    int excl = s[tid] - t;
#pragma unroll
    for (int j = 0; j < 4; j++) {
        const int idx = base + j;
        if (idx < N_NODES) row_start[idx] = excl;
        excl += v[j];
    }
    if (tid == 255) bsum[blockIdx.x] = s[255];
}

__global__ void k_scanB(int* bsum, int nb) {
    int tid = threadIdx.x;   // 64 threads, nb <= 64
    int v = (tid < nb) ? bsum[tid] : 0;
    int orig = v;
    for (int off = 1; off < 64; off <<= 1) {
        int y = __shfl_up(v, off);
        if (tid >= off) v += y;
    }
    if (tid < nb) bsum[tid] = v - orig;   // exclusive block offsets
}

// scanC: finalize row_start; write each node's self-loop into its LAST csr
// slot (rs+counts[i]; edge slots occupy rs..rs+counts[i]-1).
__global__ void k_scanC(int* __restrict__ row_start, const int* __restrict__ bsum,
                        const int* __restrict__ counts, int* __restrict__ csr) {
    int i = blockIdx.x * 256 + threadIdx.x;
    if (i < N_NODES) {
        int rs = row_start[i] + bsum[i >> 10];
        row_start[i] = rs;
        csr[rs + counts[i]] = i;
    }
}

// ---------------------------------------------------------------------------
// K_lf: fused linear(MFMA) + deterministic CSR fill (no global atomics).
// 1038 blocks: bid<1024 & (bid&3)==0 -> fill f=bid>>2 (256 blocks, r=f&15,
// c=f>>4); else linear (782 blocks). Unified 16 KB LDS (cursors 12.5 KB /
// sA 16 KB) so fill blocks no longer cap linear occupancy (R7: 25 KB).
// ---------------------------------------------------------------------------
__global__ __launch_bounds__(256) void k_lf(
    const float* __restrict__ x,
    const unsigned short* __restrict__ Bfrag,
    const float* __restrict__ att_s,
    const float* __restrict__ att_d,
    const float* __restrict__ bias,
    unsigned short* __restrict__ h_bf, unsigned int* __restrict__ z0b,
    float* __restrict__ a_src, float* __restrict__ a_dst,
    const int* __restrict__ src, const int* __restrict__ dst,
    const int* __restrict__ row_start, const int* __restrict__ part,
    int* __restrict__ csr)
{
    __shared__ __align__(16) int smem[4096];   // fill: cursors; linear: sA
    const int bid = blockIdx.x;
    const int tid = threadIdx.x;
    int lin;
    if (bid < 1024) {
        if ((bid & 3) == 0) {
            // ---------------- CSR fill ----------------
            const int f = bid >> 2;
            const int r = f & 15, c = f >> 4;
            const int nb = r * RSZ;
            for (int b = tid; b < RSZ; b += 256)
                smem[b] = row_start[nb + b] + part[(size_t)(nb + b) * NCH + c];
            __syncthreads();
            const int4* d4 = (const int4*)(dst + c * CHSZ);
            const int4* s4 = (const int4*)(src + c * CHSZ);
            for (int i = tid; i < CHSZ / 4; i += 256) {
                const int4 dv = d4[i];
                const int4 sv = s4[i];
                int b;
                b = dv.x - nb; if ((unsigned)b < (unsigned)RSZ) csr[atomicAdd(&smem[b], 1)] = sv.x;
                b = dv.y - nb; if ((unsigned)b < (unsigned)RSZ) csr[atomicAdd(&smem[b], 1)] = sv.y;
                b = dv.z - nb; if ((unsigned)b < (unsigned)RSZ) csr[atomicAdd(&smem[b], 1)] = sv.z;
                b = dv.w - nb; if ((unsigned)b < (unsigned)RSZ) csr[atomicAdd(&smem[b], 1)] = sv.w;
            }
            return;
        }
        lin = bid - (bid >> 2) - 1;          // 0..767
    } else {
        lin = bid - 256;                     // 768..781
    }

    // ---------------- linear (MFMA) ----------------
    unsigned short* sA = (unsigned short*)smem;   // [mt*4+kq][lane][j] 16 KB
    const int lane = tid & 63;
    const int w = tid >> 6;
    const int nbase = lin * 64;

    // stage A: x[64 nodes][128 k] -> bf16 fragment-major
#pragma unroll
    for (int it = 0; it < 4; it++) {
        const int p = it * 256 + tid;
        const int node = p >> 4;        // 0..63
        const int kg = p & 15;          // k-group of 8
        const int gn = nbase + node;
        float v[8];
        if (gn < N_NODES) {
            float4 u0 = *(const float4*)(x + (size_t)gn * F_IN + kg * 8);
            float4 u1 = *(const float4*)(x + (size_t)gn * F_IN + kg * 8 + 4);
            v[0] = u0.x; v[1] = u0.y; v[2] = u0.z; v[3] = u0.w;
            v[4] = u1.x; v[5] = u1.y; v[6] = u1.z; v[7] = u1.w;
        } else {
#pragma unroll
            for (int j = 0; j < 8; j++) v[j] = 0.f;
        }
        const int mt = node >> 4, lm = node & 15;
        const int kq = kg >> 2, quad = kg & 3;
        uint4 pk;
        pk.x = f2bf(v[0]) | (f2bf(v[1]) << 16);
        pk.y = f2bf(v[2]) | (f2bf(v[3]) << 16);
        pk.z = f2bf(v[4]) | (f2bf(v[5]) << 16);
        pk.w = f2bf(v[6]) | (f2bf(v[7]) << 16);
        *(uint4*)(sA + ((size_t)((mt * 4 + kq) * 64 + quad * 16 + lm)) * 8) = pk;
    }
    __syncthreads();

    const bf16x8* Bf = (const bf16x8*)Bfrag;
    f32x4 acc[4][4];
#pragma unroll
    for (int mt = 0; mt < 4; mt++)
#pragma unroll
        for (int nt = 0; nt < 4; nt++)
            acc[mt][nt] = (f32x4){0.f, 0.f, 0.f, 0.f};

#pragma unroll
    for (int kq = 0; kq < 4; kq++) {
        bf16x8 aF[4], bF[4];
#pragma unroll
        for (int nt = 0; nt < 4; nt++)
            bF[nt] = Bf[(size_t)(((w * 4 + nt) * 4 + kq) * 64 + lane)];
#pragma unroll
        for (int mt = 0; mt < 4; mt++)
            aF[mt] = *(const bf16x8*)(sA + ((size_t)((mt * 4 + kq) * 64 + lane)) * 8);
#pragma unroll
        for (int mt = 0; mt < 4; mt++)
#pragma unroll
            for (int nt = 0; nt < 4; nt++)
                acc[mt][nt] = __builtin_amdgcn_mfma_f32_16x16x32_bf16(
                    aF[mt], bF[nt], acc[mt][nt], 0, 0, 0);
    }

    // epilogue: D[row=(lane>>4)*4+r][col=lane&15]
    const int row4 = (lane >> 4) * 4;
    const int cl = lane & 15;
#pragma unroll
    for (int mt = 0; mt < 4; mt++) {
#pragma unroll
        for (int nt = 0; nt < 4; nt++) {
            const int cc = w * 64 + nt * 16 + cl;   // wave-uniform branch below
            f32x4 d = acc[mt][nt];
            if (cc < 128) {
                const float asv = att_s[cc];
                const float adv = att_d[cc];
                float ps[4], pd[4];
#pragma unroll
                for (int rr = 0; rr < 4; rr++) { ps[rr] = d[rr] * asv; pd[rr] = d[rr] * adv; }
#pragma unroll
                for (int m = 1; m <= 8; m <<= 1) {
#pragma unroll
                    for (int rr = 0; rr < 4; rr++) {
                        ps[rr] += __shfl_xor(ps[rr], m);
                        pd[rr] += __shfl_xor(pd[rr], m);
                    }
                }
                const int head = w * 4 + nt;
#pragma unroll
                for (int rr = 0; rr < 4; rr++) {
                    const int gn = nbase + mt * 16 + row4 + rr;
                    if (gn < N_NODES) {
                        h_bf[(size_t)gn * HC + cc] = (unsigned short)f2bf(d[rr]);
                        if (cl == 0) {
                            a_src[gn * 8 + head] = ps[rr];
                            a_dst[gn * 8 + head] = pd[rr];
                        }
                    }
                }
            } else {
                const int cz = cc - 128;
                const float bv = bias[cz];
#pragma unroll
                for (int rr = 0; rr < 4; rr++) {
                    const int gn = nbase + mt * 16 + row4 + rr;
                    const float val = 0.1f * d[rr] + bv;
                    const float oth = __shfl_xor(val, 1);   // neighbor col
                    if ((cl & 1) == 0 && gn < N_NODES) {
                        z0b[(size_t)gn * 64 + (cz >> 1)] =
                            f2bf(val) | (f2bf(oth) << 16);
                    }
                }
            }
        }
    }
}

// ---------------------------------------------------------------------------
// K_agg: per-node aggregation + skip + LN + ELU.
// 2 nodes per wave (32 lanes, uint2 = 4 cols/lane); batch-8 gathers
// (24 loads in flight per half-wave); tail edges weight-masked.
// cnt = counts[n]+1 (self-loop = last slot). Softmax max-subtraction
// cancels in (sum w*h)/(sum w); |e| small -> no overflow.
// ---------------------------------------------------------------------------
__global__ __launch_bounds__(256) void k_agg(
    const uint2* __restrict__ h2,    // bf16 pairs, [N][32] uint2
    const uint2* __restrict__ z0b,   // bf16 pairs, [N][32] uint2
    const float* __restrict__ a_src, const float* __restrict__ a_dst,
    const int* __restrict__ row_start, const int* __restrict__ counts,
    const int* __restrict__ csr,
    const float* __restrict__ gamma, const float* __restrict__ beta,
    float* __restrict__ out)
{
    const int tid = threadIdx.x;
    const int lane = tid & 63;
    const int l = lane & 31;                 // lane within node-half
    const int n = blockIdx.x * 8 + ((tid >> 6) << 1) + (lane >> 5);
    const int head = l >> 2;                 // cols 4l..4l+3 share a head

    const float adn = a_dst[n * 8 + head];
    const int rs = row_start[n];
    const int cnt = counts[n] + 1;           // + self-loop

    float d_acc = 0.f, a0 = 0.f, a1 = 0.f, a2 = 0.f, a3 = 0.f;
    for (int i = 0; i < cnt; i += 8) {
        int s[8]; float ae[8], mk[8]; uint2 hp[8];
#pragma unroll
        for (int j = 0; j < 8; j++) {
            const int e = i + j;
            const int ec = (e < cnt) ? e : (cnt - 1);
            mk[j] = (e < cnt) ? 1.f : 0.f;
            s[j] = csr[rs + ec];
        }
#pragma unroll
        for (int j = 0; j < 8; j++) ae[j] = a_src[s[j] * 8 + head];
#pragma unroll
        for (int j = 0; j < 8; j++) hp[j] = h2[(size_t)s[j] * 32 + l];
#pragma unroll
        for (int j = 0; j < 8; j++) {
            float e = ae[j] + adn;
            e = (e > 0.f) ? e : 0.2f * e;      // leaky_relu(0.2)
            const float wgt = __expf(e) * mk[j];
            d_acc += wgt;
            a0 += wgt * bf2f(hp[j].x & 0xffffu);
            a1 += wgt * bf2f(hp[j].x >> 16);
            a2 += wgt * bf2f(hp[j].y & 0xffffu);
            a3 += wgt * bf2f(hp[j].y >> 16);
        }
    }
    const float inv = 1.0f / d_acc;
    const uint2 zp = z0b[(size_t)n * 32 + l];
    float y0 = a0 * inv + bf2f(zp.x & 0xffffu);
    float y1 = a1 * inv + bf2f(zp.x >> 16);
    float y2 = a2 * inv + bf2f(zp.y & 0xffffu);
    float y3 = a3 * inv + bf2f(zp.y >> 16);

    // LayerNorm over 128 cols (32-lane half-wave reduce)
    float ss = y0 + y1 + y2 + y3;
#pragma unroll
    for (int off = 1; off < 32; off <<= 1) ss += __shfl_xor(ss, off);
    const float mu = ss * (1.0f / 128.0f);
    const float d0 = y0 - mu, d1 = y1 - mu, d2 = y2 - mu, d3 = y3 - mu;
    float vs = d0 * d0 + d1 * d1 + d2 * d2 + d3 * d3;
#pragma unroll
    for (int off = 1; off < 32; off <<= 1) vs += __shfl_xor(vs, off);
    const float rstd = rsqrtf(vs * (1.0f / 128.0f) + 1e-5f);

    const float4 gv = *(const float4*)(gamma + l * 4);
    const float4 bv = *(const float4*)(beta + l * 4);
    float o0 = d0 * rstd * gv.x + bv.x;
    float o1 = d1 * rstd * gv.y + bv.y;
    float o2 = d2 * rstd * gv.z + bv.z;
    float o3 = d3 * rstd * gv.w + bv.w;
    o0 = (o0 > 0.f) ? o0 : (__expf(o0) - 1.0f);   // ELU
    o1 = (o1 > 0.f) ? o1 : (__expf(o1) - 1.0f);
    o2 = (o2 > 0.f) ? o2 : (__expf(o2) - 1.0f);
    o3 = (o3 > 0.f) ? o3 : (__expf(o3) - 1.0f);

    *(float4*)(out + (size_t)n * HC + l * 4) = make_float4(o0, o1, o2, o3);
}

// ---------------------------------------------------------------------------
extern "C" void kernel_launch(void* const* d_in, const int* in_sizes, int n_in,
                              void* d_out, int out_size, void* d_ws, size_t ws_size,
                              hipStream_t stream) {
    const float* x   = (const float*)d_in[0];
    const int*   ei  = (const int*)d_in[1];
    const float* Wg  = (const float*)d_in[2];
    const float* as_ = (const float*)d_in[3];
    const float* ad_ = (const float*)d_in[4];
    const float* bg  = (const float*)d_in[5];
    const float* Wsk = (const float*)d_in[6];
    const float* gm  = (const float*)d_in[7];
    const float* bt  = (const float*)d_in[8];
    float* out = (float*)d_out;

    // workspace layout (bytes), ~35.9 MB total
    char* wsb = (char*)d_ws;
    unsigned short* h_bf  = (unsigned short*)wsb;              // [N][128] bf16
    unsigned int*   z0b   = (unsigned int*)(wsb + 12800000);   // [N][64] bf16x2
    float*          a_src = (float*)(wsb + 25600000);          // [N][8]
    float*          a_dst = (float*)(wsb + 27200000);          // [N][8]
    unsigned short* Bfrag = (unsigned short*)(wsb + 28800000); // 64 KB
    int*   counts = (int*)(wsb + 28865536);                    // 50048
    int*   row_st = (int*)(wsb + 29065728);                    // 50048
    int*   bsum   = (int*)(wsb + 29265920);                    // 256
    int*   csr    = (int*)(wsb + 29266944);                    // 850000
    int*   part   = (int*)(wsb + 32666944);                    // 800000

    const int* src = ei;
    const int* dst = ei + N_EDGES;

    k_hist <<<272, 256, 0, stream>>>(dst, Wg, Wsk, Bfrag, part);
    k_scanA<<<49, 256, 0, stream>>>(part, counts, row_st, bsum);
    k_scanB<<<1, 64, 0, stream>>>(bsum, 49);
    k_scanC<<<196, 256, 0, stream>>>(row_st, bsum, counts, csr);
    k_lf   <<<1038, 256, 0, stream>>>(x, Bfrag, as_, ad_, bg, h_bf, z0b,
                                      a_src, a_dst, src, dst, row_st, part, csr);
    k_agg  <<<N_NODES / 8, 256, 0, stream>>>((const uint2*)h_bf, (const uint2*)z0b,
                                             a_src, a_dst, row_st, counts, csr,
                                             gm, bt, out);
}

// Round 9
// 210.413 us; speedup vs baseline: 1.2012x; 1.2012x over previous
//
#include <hip/hip_runtime.h>
#include <hip/hip_bf16.h>

#define N_NODES 50000
#define N_EDGES 800000
#define F_IN    128
#define HC      128      // H*C
#define NR      8        // node ranges (XCD-pinned: fill block bid%8 == r)
#define RSZ     6250     // nodes per range
#define NCH     16       // edge chunks
#define CHSZ    50000    // edges per chunk
#define NP      50048    // padded node stride for part_t[c][n]

typedef __attribute__((ext_vector_type(8))) short bf16x8;
typedef __attribute__((ext_vector_type(4))) float f32x4;

__device__ __forceinline__ float bf2f(unsigned int u16) {
    return __uint_as_float(u16 << 16);
}
__device__ __forceinline__ unsigned int f2bf(float f) {
    unsigned int u = __float_as_uint(f);
    return (u + 0x7fffu + ((u >> 16) & 1u)) >> 16;   // RNE
}

// ---------------------------------------------------------------------------
// K_hist: blocks 0..127 = LDS sub-histogram for (range r=bid&7, chunk
// c=bid>>3); partials to part_t[c*NP + node] (COALESCED — transposed layout).
// Blocks 128..143: pack [Wg|Ws] -> Bfrag (MFMA-B fragment-major bf16).
// No global atomics anywhere in the CSR pipeline.
// ---------------------------------------------------------------------------
__global__ __launch_bounds__(256) void k_hist(
    const int* __restrict__ dst,
    const float* __restrict__ Wg, const float* __restrict__ Ws,
    unsigned short* __restrict__ Bfrag, int* __restrict__ part)
{
    const int bid = blockIdx.x;
    const int tid = threadIdx.x;
    if (bid < 128) {
        __shared__ int hist[RSZ];
        const int r = bid & 7, c = bid >> 3;
        const int nb = r * RSZ;
        for (int i = tid; i < RSZ; i += 256) hist[i] = 0;
        __syncthreads();
        const int4* d4 = (const int4*)(dst + c * CHSZ);
        for (int i = tid; i < CHSZ / 4; i += 256) {
            const int4 v = d4[i];
            int b;
            b = v.x - nb; if ((unsigned)b < (unsigned)RSZ) atomicAdd(&hist[b], 1);
            b = v.y - nb; if ((unsigned)b < (unsigned)RSZ) atomicAdd(&hist[b], 1);
            b = v.z - nb; if ((unsigned)b < (unsigned)RSZ) atomicAdd(&hist[b], 1);
            b = v.w - nb; if ((unsigned)b < (unsigned)RSZ) atomicAdd(&hist[b], 1);
        }
        __syncthreads();
        for (int i = tid; i < RSZ; i += 256)
            part[(size_t)c * NP + nb + i] = hist[i];
    } else {
        const int g = (bid - 128) * 256 + tid;
        if (g < 4096) {
            const int lane = g & 63;
            const int kq = (g >> 6) & 3;
            const int nt = g >> 8;           // 0..15
            const int cc = nt * 16 + (lane & 15);
            const int kbase = kq * 32 + (lane >> 4) * 8;
            const float* Wsel = (cc < 128) ? (Wg + cc) : (Ws + cc - 128);
            unsigned int pk[4];
#pragma unroll
            for (int p = 0; p < 4; p++) {
                const float v0 = Wsel[(size_t)(kbase + 2 * p) * HC];
                const float v1 = Wsel[(size_t)(kbase + 2 * p + 1) * HC];
                pk[p] = f2bf(v0) | (f2bf(v1) << 16);
            }
            *(uint4*)(Bfrag + (size_t)g * 8) = make_uint4(pk[0], pk[1], pk[2], pk[3]);
        }
    }
}

// ---------------------------------------------------------------------------
// K_scanA (merge fused): per node, chunk-exclusive-prefix part_t in place
// (16 coalesced passes), counts[n]=total; block-exclusive-scan of (counts+1)
// -> row_start; block sums -> bsum. Multi-block (single-block = R5 regress).
// ---------------------------------------------------------------------------
__global__ __launch_bounds__(256) void k_scanA(
    int* __restrict__ part, int* __restrict__ counts,
    int* __restrict__ row_start, int* __restrict__ bsum)
{
    __shared__ int s[256];
    const int tid = threadIdx.x;
    const int base = blockIdx.x * 1024 + tid * 4;
    int v[4]; int t = 0;
#pragma unroll
    for (int j = 0; j < 4; j++) {
        const int idx = base + j;
        if (idx < N_NODES) {
            int run = 0;
#pragma unroll
            for (int c = 0; c < 16; c++) {
                int* p = part + (size_t)c * NP + idx;
                const int q = *p;
                *p = run;
                run += q;
            }
            counts[idx] = run;
            v[j] = run + 1;                  // +1 = self-loop
        } else v[j] = 0;
        t += v[j];
    }
    s[tid] = t;
    __syncthreads();
    for (int off = 1; off < 256; off <<= 1) {
        int add = (tid >= off) ? s[tid - off] : 0;
        __syncthreads();
        s[tid] += add;
        __syncthreads();
    }
    int excl = s[tid] - t;
#pragma unroll
    for (int j = 0; j < 4; j++) {
        const int idx = base + j;
        if (idx < N_NODES) row_start[idx] = excl;
        excl += v[j];
    }
    if (tid == 255) bsum[blockIdx.x] = s[255];
}

__global__ void k_scanB(int* bsum, int nb) {
    int tid = threadIdx.x;   // 64 threads, nb <= 64
    int v = (tid < nb) ? bsum[tid] : 0;
    int orig = v;
    for (int off = 1; off < 64; off <<= 1) {
        int y = __shfl_up(v, off);
        if (tid >= off) v += y;
    }
    if (tid < nb) bsum[tid] = v - orig;   // exclusive block offsets
}

// scanC: finalize row_start; write each node's self-loop into its LAST csr
// slot (rs+counts[i]; edge slots occupy rs..rs+counts[i]-1).
__global__ void k_scanC(int* __restrict__ row_start, const int* __restrict__ bsum,
                        const int* __restrict__ counts, int* __restrict__ csr) {
    int i = blockIdx.x * 256 + threadIdx.x;
    if (i < N_NODES) {
        int rs = row_start[i] + bsum[i >> 10];
        row_start[i] = rs;
        csr[rs + counts[i]] = i;
    }
}

// ---------------------------------------------------------------------------
// K_lf: fused linear(MFMA) + deterministic CSR fill (R7-proven structure:
// fill at bid<256, pos<8 so bid%8 == r — XCD-pinned; breaking this cost
// +40 us in R8). Fill: LDS cursors = row_start + part_t (both coalesced);
// LDS-atomic rank -> scatter csr within range r's slice. No global atomics.
// Linear: h_bf16=x@Wg, z0(bf16)=bias+0.1*(x@Ws), att dots.
// ---------------------------------------------------------------------------
__global__ __launch_bounds__(256) void k_lf(
    const float* __restrict__ x,
    const unsigned short* __restrict__ Bfrag,
    const float* __restrict__ att_s,
    const float* __restrict__ att_d,
    const float* __restrict__ bias,
    unsigned short* __restrict__ h_bf, unsigned int* __restrict__ z0b,
    float* __restrict__ a_src, float* __restrict__ a_dst,
    const int* __restrict__ src, const int* __restrict__ dst,
    const int* __restrict__ row_start, const int* __restrict__ part,
    int* __restrict__ csr)
{
    __shared__ __align__(16) int smem[RSZ];   // fill: cursors; linear: sA alias
    const int bid = blockIdx.x;
    const int tid = threadIdx.x;
    int lin = -1, r = 0, c = 0;
    if (bid < 256) {
        const int g = bid >> 4, pos = bid & 15;
        if (pos < 8) { r = pos; c = g; }           // bid%8 == r  (XCD pin)
        else lin = g * 8 + (pos - 8);
    } else {
        lin = 128 + (bid - 256);
    }

    if (lin < 0) {
        // ---------------- CSR fill ----------------
        const int nb = r * RSZ;
        for (int b = tid; b < RSZ; b += 256)
            smem[b] = row_start[nb + b] + part[(size_t)c * NP + nb + b];
        __syncthreads();
        const int4* d4 = (const int4*)(dst + c * CHSZ);
        const int4* s4 = (const int4*)(src + c * CHSZ);
        for (int i = tid; i < CHSZ / 4; i += 256) {
            const int4 dv = d4[i];
            const int4 sv = s4[i];
            int b;
            b = dv.x - nb; if ((unsigned)b < (unsigned)RSZ) csr[atomicAdd(&smem[b], 1)] = sv.x;
            b = dv.y - nb; if ((unsigned)b < (unsigned)RSZ) csr[atomicAdd(&smem[b], 1)] = sv.y;
            b = dv.z - nb; if ((unsigned)b < (unsigned)RSZ) csr[atomicAdd(&smem[b], 1)] = sv.z;
            b = dv.w - nb; if ((unsigned)b < (unsigned)RSZ) csr[atomicAdd(&smem[b], 1)] = sv.w;
        }
        return;
    }

    // ---------------- linear (MFMA) ----------------
    unsigned short* sA = (unsigned short*)smem;   // [mt*4+kq][lane][j] 16 KB
    const int lane = tid & 63;
    const int w = tid >> 6;
    const int nbase = lin * 64;

    // stage A: x[64 nodes][128 k] -> bf16 fragment-major
#pragma unroll
    for (int it = 0; it < 4; it++) {
        const int p = it * 256 + tid;
        const int node = p >> 4;        // 0..63
        const int kg = p & 15;          // k-group of 8
        const int gn = nbase + node;
        float v[8];
        if (gn < N_NODES) {
            float4 u0 = *(const float4*)(x + (size_t)gn * F_IN + kg * 8);
            float4 u1 = *(const float4*)(x + (size_t)gn * F_IN + kg * 8 + 4);
            v[0] = u0.x; v[1] = u0.y; v[2] = u0.z; v[3] = u0.w;
            v[4] = u1.x; v[5] = u1.y; v[6] = u1.z; v[7] = u1.w;
        } else {
#pragma unroll
            for (int j = 0; j < 8; j++) v[j] = 0.f;
        }
        const int mt = node >> 4, lm = node & 15;
        const int kq = kg >> 2, quad = kg & 3;
        uint4 pk;
        pk.x = f2bf(v[0]) | (f2bf(v[1]) << 16);
        pk.y = f2bf(v[2]) | (f2bf(v[3]) << 16);
        pk.z = f2bf(v[4]) | (f2bf(v[5]) << 16);
        pk.w = f2bf(v[6]) | (f2bf(v[7]) << 16);
        *(uint4*)(sA + ((size_t)((mt * 4 + kq) * 64 + quad * 16 + lm)) * 8) = pk;
    }
    __syncthreads();

    const bf16x8* Bf = (const bf16x8*)Bfrag;
    f32x4 acc[4][4];
#pragma unroll
    for (int mt = 0; mt < 4; mt++)
#pragma unroll
        for (int nt = 0; nt < 4; nt++)
            acc[mt][nt] = (f32x4){0.f, 0.f, 0.f, 0.f};

#pragma unroll
    for (int kq = 0; kq < 4; kq++) {
        bf16x8 aF[4], bF[4];
#pragma unroll
        for (int nt = 0; nt < 4; nt++)
            bF[nt] = Bf[(size_t)(((w * 4 + nt) * 4 + kq) * 64 + lane)];
#pragma unroll
        for (int mt = 0; mt < 4; mt++)
            aF[mt] = *(const bf16x8*)(sA + ((size_t)((mt * 4 + kq) * 64 + lane)) * 8);
#pragma unroll
        for (int mt = 0; mt < 4; mt++)
#pragma unroll
            for (int nt = 0; nt < 4; nt++)
                acc[mt][nt] = __builtin_amdgcn_mfma_f32_16x16x32_bf16(
                    aF[mt], bF[nt], acc[mt][nt], 0, 0, 0);
    }

    // epilogue: D[row=(lane>>4)*4+r][col=lane&15]
    const int row4 = (lane >> 4) * 4;
    const int cl = lane & 15;
#pragma unroll
    for (int mt = 0; mt < 4; mt++) {
#pragma unroll
        for (int nt = 0; nt < 4; nt++) {
            const int cc = w * 64 + nt * 16 + cl;   // wave-uniform branch below
            f32x4 d = acc[mt][nt];
            if (cc < 128) {
                const float asv = att_s[cc];
                const float adv = att_d[cc];
                float ps[4], pd[4];
#pragma unroll
                for (int rr = 0; rr < 4; rr++) { ps[rr] = d[rr] * asv; pd[rr] = d[rr] * adv; }
#pragma unroll
                for (int m = 1; m <= 8; m <<= 1) {
#pragma unroll
                    for (int rr = 0; rr < 4; rr++) {
                        ps[rr] += __shfl_xor(ps[rr], m);
                        pd[rr] += __shfl_xor(pd[rr], m);
                    }
                }
                const int head = w * 4 + nt;
#pragma unroll
                for (int rr = 0; rr < 4; rr++) {
                    const int gn = nbase + mt * 16 + row4 + rr;
                    if (gn < N_NODES) {
                        h_bf[(size_t)gn * HC + cc] = (unsigned short)f2bf(d[rr]);
                        if (cl == 0) {
                            a_src[gn * 8 + head] = ps[rr];
                            a_dst[gn * 8 + head] = pd[rr];
                        }
                    }
                }
            } else {
                const int cz = cc - 128;
                const float bv = bias[cz];
#pragma unroll
                for (int rr = 0; rr < 4; rr++) {
                    const int gn = nbase + mt * 16 + row4 + rr;
                    const float val = 0.1f * d[rr] + bv;
                    const float oth = __shfl_xor(val, 1);   // neighbor col
                    if ((cl & 1) == 0 && gn < N_NODES) {
                        z0b[(size_t)gn * 64 + (cz >> 1)] =
                            f2bf(val) | (f2bf(oth) << 16);
                    }
                }
            }
        }
    }
}

// ---------------------------------------------------------------------------
// K_agg: per-node aggregation + skip + LN + ELU.
// 2 nodes per wave (32 lanes, uint2 = 4 cols/lane); batch-8 gathers
// (24 loads in flight per half-wave); tail edges weight-masked.
// cnt = counts[n]+1 (self-loop = last slot). Softmax max-subtraction
// cancels in (sum w*h)/(sum w); |e| small -> no overflow.
// ---------------------------------------------------------------------------
__global__ __launch_bounds__(256) void k_agg(
    const uint2* __restrict__ h2,    // bf16 pairs, [N][32] uint2
    const uint2* __restrict__ z0b,   // bf16 pairs, [N][32] uint2
    const float* __restrict__ a_src, const float* __restrict__ a_dst,
    const int* __restrict__ row_start, const int* __restrict__ counts,
    const int* __restrict__ csr,
    const float* __restrict__ gamma, const float* __restrict__ beta,
    float* __restrict__ out)
{
    const int tid = threadIdx.x;
    const int lane = tid & 63;
    const int l = lane & 31;                 // lane within node-half
    const int n = blockIdx.x * 8 + ((tid >> 6) << 1) + (lane >> 5);
    const int head = l >> 2;                 // cols 4l..4l+3 share a head

    const float adn = a_dst[n * 8 + head];
    const int rs = row_start[n];
    const int cnt = counts[n] + 1;           // + self-loop

    float d_acc = 0.f, a0 = 0.f, a1 = 0.f, a2 = 0.f, a3 = 0.f;
    for (int i = 0; i < cnt; i += 8) {
        int s[8]; float ae[8], mk[8]; uint2 hp[8];
#pragma unroll
        for (int j = 0; j < 8; j++) {
            const int e = i + j;
            const int ec = (e < cnt) ? e : (cnt - 1);
            mk[j] = (e < cnt) ? 1.f : 0.f;
            s[j] = csr[rs + ec];
        }
#pragma unroll
        for (int j = 0; j < 8; j++) ae[j] = a_src[s[j] * 8 + head];
#pragma unroll
        for (int j = 0; j < 8; j++) hp[j] = h2[(size_t)s[j] * 32 + l];
#pragma unroll
        for (int j = 0; j < 8; j++) {
            float e = ae[j] + adn;
            e = (e > 0.f) ? e : 0.2f * e;      // leaky_relu(0.2)
            const float wgt = __expf(e) * mk[j];
            d_acc += wgt;
            a0 += wgt * bf2f(hp[j].x & 0xffffu);
            a1 += wgt * bf2f(hp[j].x >> 16);
            a2 += wgt * bf2f(hp[j].y & 0xffffu);
            a3 += wgt * bf2f(hp[j].y >> 16);
        }
    }
    const float inv = 1.0f / d_acc;
    const uint2 zp = z0b[(size_t)n * 32 + l];
    float y0 = a0 * inv + bf2f(zp.x & 0xffffu);
    float y1 = a1 * inv + bf2f(zp.x >> 16);
    float y2 = a2 * inv + bf2f(zp.y & 0xffffu);
    float y3 = a3 * inv + bf2f(zp.y >> 16);

    // LayerNorm over 128 cols (32-lane half-wave reduce)
    float ss = y0 + y1 + y2 + y3;
#pragma unroll
    for (int off = 1; off < 32; off <<= 1) ss += __shfl_xor(ss, off);
    const float mu = ss * (1.0f / 128.0f);
    const float d0 = y0 - mu, d1 = y1 - mu, d2 = y2 - mu, d3 = y3 - mu;
    float vs = d0 * d0 + d1 * d1 + d2 * d2 + d3 * d3;
#pragma unroll
    for (int off = 1; off < 32; off <<= 1) vs += __shfl_xor(vs, off);
    const float rstd = rsqrtf(vs * (1.0f / 128.0f) + 1e-5f);

    const float4 gv = *(const float4*)(gamma + l * 4);
    const float4 bv = *(const float4*)(beta + l * 4);
    float o0 = d0 * rstd * gv.x + bv.x;
    float o1 = d1 * rstd * gv.y + bv.y;
    float o2 = d2 * rstd * gv.z + bv.z;
    float o3 = d3 * rstd * gv.w + bv.w;
    o0 = (o0 > 0.f) ? o0 : (__expf(o0) - 1.0f);   // ELU
    o1 = (o1 > 0.f) ? o1 : (__expf(o1) - 1.0f);
    o2 = (o2 > 0.f) ? o2 : (__expf(o2) - 1.0f);
    o3 = (o3 > 0.f) ? o3 : (__expf(o3) - 1.0f);

    *(float4*)(out + (size_t)n * HC + l * 4) = make_float4(o0, o1, o2, o3);
}

// ---------------------------------------------------------------------------
extern "C" void kernel_launch(void* const* d_in, const int* in_sizes, int n_in,
                              void* d_out, int out_size, void* d_ws, size_t ws_size,
                              hipStream_t stream) {
    const float* x   = (const float*)d_in[0];
    const int*   ei  = (const int*)d_in[1];
    const float* Wg  = (const float*)d_in[2];
    const float* as_ = (const float*)d_in[3];
    const float* ad_ = (const float*)d_in[4];
    const float* bg  = (const float*)d_in[5];
    const float* Wsk = (const float*)d_in[6];
    const float* gm  = (const float*)d_in[7];
    const float* bt  = (const float*)d_in[8];
    float* out = (float*)d_out;

    // workspace layout (bytes), ~35.9 MB total
    char* wsb = (char*)d_ws;
    unsigned short* h_bf  = (unsigned short*)wsb;              // [N][128] bf16
    unsigned int*   z0b   = (unsigned int*)(wsb + 12800000);   // [N][64] bf16x2
    float*          a_src = (float*)(wsb + 25600000);          // [N][8]
    float*          a_dst = (float*)(wsb + 27200000);          // [N][8]
    unsigned short* Bfrag = (unsigned short*)(wsb + 28800000); // 64 KB
    int*   counts = (int*)(wsb + 28865536);                    // 50048
    int*   row_st = (int*)(wsb + 29065728);                    // 50048
    int*   bsum   = (int*)(wsb + 29265920);                    // 256
    int*   csr    = (int*)(wsb + 29266944);                    // 850000
    int*   part   = (int*)(wsb + 32666944);                    // 16*NP = 800768

    const int* src = ei;
    const int* dst = ei + N_EDGES;

    k_hist <<<144, 256, 0, stream>>>(dst, Wg, Wsk, Bfrag, part);
    k_scanA<<<49, 256, 0, stream>>>(part, counts, row_st, bsum);
    k_scanB<<<1, 64, 0, stream>>>(bsum, 49);
    k_scanC<<<196, 256, 0, stream>>>(row_st, bsum, counts, csr);
    k_lf   <<<910, 256, 0, stream>>>(x, Bfrag, as_, ad_, bg, h_bf, z0b,
                                     a_src, a_dst, src, dst, row_st, part, csr);
    k_agg  <<<N_NODES / 8, 256, 0, stream>>>((const uint2*)h_bf, (const uint2*)z0b,
                                             a_src, a_dst, row_st, counts, csr,
                                             gm, bt, out);
}